// Round 8
// baseline (443.804 us; speedup 1.0000x reference)
//
#include <hip/hip_runtime.h>

// GCN 2-layer, N=100000, E=3200000, 13 -> 32 -> 16.
// Pipeline: coarse bucket sort by dst>>9 (512-node buckets) -> per-bucket LDS
// counting sort ONCE to compact global srcs/off/dis -> 4 reduction-free
// aggregation passes: 2 lanes per node (float4 each), serial edge loop with
// srcs prefetch, gathering from 3.2MB L2-resident half-channel tables.
// Messages premultiplied by dis[src]; dis[dst] + bias applied at finalize.

constexpr int N_NODES = 100000;
constexpr int N_EDGES = 3200000;
constexpr int IN_CH  = 13;
constexpr int HID_CH = 32;
constexpr int LAT_CH = 16;

constexpr int BSZ  = 512;                       // nodes per bucket
constexpr int NBKT = (N_NODES + BSZ - 1) / BSZ; // 196
constexpr int BCAP = 18432;                     // mean 16384, sd 128 -> 16 sigma
constexpr int TILE = 16384;                     // edges per binA block (1024 thr x 16)

__global__ __launch_bounds__(256) void k_zero(int* __restrict__ bcur) {
    int i = threadIdx.x;
    if (i < NBKT) bcur[i] = 0;
}

// bucket by dst>>9; packed word = (dst&511)<<17 | src (26 bits).
// Edges staged in registers between hist and scatter (one global read).
__global__ __launch_bounds__(1024) void k_binA(const int* __restrict__ src,
                                               const int* __restrict__ dst,
                                               int* __restrict__ bcur,
                                               int* __restrict__ buckets) {
    __shared__ int h[NBKT], st[NBKT], cur[NBKT];
    int tid = threadIdx.x;
    if (tid < NBKT) h[tid] = 0;
    __syncthreads();
    int e0 = blockIdx.x * TILE;
    int rs[16], rd[16];
#pragma unroll
    for (int i = 0; i < 16; ++i) {
        int e = e0 + tid + i * 1024;
        if (e < N_EDGES) {
            rs[i] = src[e]; rd[i] = dst[e];
            atomicAdd(&h[rd[i] >> 9], 1);
        } else rd[i] = -1;
    }
    __syncthreads();
    if (tid < NBKT) {
        int c = h[tid];
        st[tid] = c ? atomicAdd(&bcur[tid], c) : 0;
        cur[tid] = 0;
    }
    __syncthreads();
#pragma unroll
    for (int i = 0; i < 16; ++i) {
        if (rd[i] >= 0) {
            int b = rd[i] >> 9;
            int p = st[b] + atomicAdd(&cur[b], 1);
            if (p < BCAP) buckets[(size_t)b * BCAP + p] = rs[i] | ((rd[i] & 511) << 17);
        }
    }
}

// exclusive scan of clamped bucket counts; also writes off[N] sentinel
__global__ __launch_bounds__(256) void k_scanTop(const int* __restrict__ bcur,
                                                 int* __restrict__ bbase,
                                                 int* __restrict__ off) {
    __shared__ int v[256];
    int tid = threadIdx.x;
    int c = (tid < NBKT) ? min(bcur[tid], BCAP) : 0;
    v[tid] = c;
    __syncthreads();
    for (int d = 1; d < 256; d <<= 1) {
        int a = v[tid];
        int u = (tid >= d) ? v[tid - d] : 0;
        __syncthreads();
        v[tid] = a + u;
        __syncthreads();
    }
    if (tid < NBKT) bbase[tid] = v[tid] - c;
    if (tid == 255) off[N_NODES] = v[255];
}

// per-bucket counting sort ONCE: reg-staged words (const-index unroll),
// LDS hist over 512 nodes -> scan -> compact global srcs; emits off, dis.
__global__ __launch_bounds__(1024) void k_sortB(const int* __restrict__ bcur,
                                                const int* __restrict__ bbase,
                                                const int* __restrict__ buckets,
                                                int* __restrict__ off,
                                                float* __restrict__ dis,
                                                int* __restrict__ srcs) {
    __shared__ int h[BSZ], ex[BSZ], cur[BSZ];
    int b = blockIdx.x, tid = threadIdx.x;
    int cnt = min(bcur[b], BCAP);
    int base = bbase[b];
    const int* bw = buckets + (size_t)b * BCAP;
    if (tid < BSZ) h[tid] = 0;
    __syncthreads();
    int rw[18];                               // BCAP/1024 = 18
#pragma unroll
    for (int i = 0; i < 18; ++i) {
        int idx = tid + i * 1024;
        rw[i] = (idx < cnt) ? __builtin_nontemporal_load(bw + idx) : -1;
        if (rw[i] >= 0) atomicAdd(&h[rw[i] >> 17], 1);
    }
    __syncthreads();
    if (tid < BSZ) ex[tid] = h[tid];
    __syncthreads();
    for (int d = 1; d < BSZ; d <<= 1) {       // inclusive scan over 512
        int a = 0, u = 0;
        if (tid < BSZ) { a = ex[tid]; if (tid >= d) u = ex[tid - d]; }
        __syncthreads();
        if (tid < BSZ) ex[tid] = a + u;
        __syncthreads();
    }
    if (tid < BSZ) {
        int excl = ex[tid] - h[tid];
        int node = b * BSZ + tid;
        if (node < N_NODES) {
            off[node] = base + excl;
            dis[node] = rsqrtf((float)(h[tid] + 1));   // +1 self-loop
        }
        cur[tid] = excl;
    }
    __syncthreads();
#pragma unroll
    for (int i = 0; i < 18; ++i) {
        if (rw[i] >= 0) {
            int p = atomicAdd(&cur[rw[i] >> 17], 1);
            srcs[base + p] = rw[i] & 131071;
        }
    }
}

// split 16-ch (13 real + 3 zero) premultiplied features into two 8-ch tables
__global__ __launch_bounds__(256) void k_xn(const float* __restrict__ x,
                                            const float* __restrict__ dis,
                                            float* __restrict__ xnA,
                                            float* __restrict__ xnB) {
    int idx = blockIdx.x * 256 + threadIdx.x;
    if (idx >= N_NODES * 16) return;
    int node = idx >> 4, c = idx & 15;
    float v = (c < IN_CH) ? x[node * IN_CH + c] * dis[node] : 0.f;
    if (c < 8) xnA[node * 8 + c] = v;
    else       xnB[node * 8 + (c - 8)] = v;
}

// Reduction-free aggregation: 2 lanes per node (lane q owns channels 4q..4q+3
// as a float4 accumulator), 32 nodes per wave, serial edge loop with 1-deep
// srcs prefetch. 1 line request per edge (2 lanes share the 32B entry).
// outp[node*ostride + q*4 .. +3] = dis[node]*(sum + tab[node]) (+ bias)
__global__ __launch_bounds__(256) void k_agg(const int* __restrict__ off,
                                             const int* __restrict__ srcs,
                                             const float* __restrict__ tab,   // N x 8
                                             const float* __restrict__ dis,
                                             const float* __restrict__ bias,  // 8 floats or null
                                             float* __restrict__ outp,
                                             int ostride) {
    int gtid = blockIdx.x * 256 + threadIdx.x;
    int wave = gtid >> 6;
    int lane = threadIdx.x & 63;
    int g = lane >> 1, q = lane & 1;
    int node = wave * 32 + g;
    bool valid = node < N_NODES;
    int beg = 0, end = 0;
    if (valid) { beg = off[node]; end = off[node + 1]; }
    float a0 = 0.f, a1 = 0.f, a2 = 0.f, a3 = 0.f;
    int k = beg;
    int s = (k < end) ? __builtin_nontemporal_load(srcs + k) : -1;
    while (s >= 0) {
        int kn = k + 1;
        int sn = (kn < end) ? __builtin_nontemporal_load(srcs + kn) : -1;  // prefetch
        const float4 v = *(const float4*)(tab + (size_t)s * 8 + q * 4);
        a0 += v.x; a1 += v.y; a2 += v.z; a3 += v.w;
        s = sn; k = kn;
    }
    if (valid) {
        const float4 self = *(const float4*)(tab + (size_t)node * 8 + q * 4);
        float dn = dis[node];
        float4 r;
        r.x = dn * (a0 + self.x);
        r.y = dn * (a1 + self.y);
        r.z = dn * (a2 + self.z);
        r.w = dn * (a3 + self.w);
        if (bias) {
            const float4 bq = *(const float4*)(bias + q * 4);
            r.x += bq.x; r.y += bq.y; r.z += bq.z; r.w += bq.w;
        }
        *(float4*)(outp + (size_t)node * ostride + q * 4) = r;
    }
}

// fused: hw{A,B} = (relu(s1 @ W1 + b1) @ W2) * dis   (split in/out tables)
__global__ __launch_bounds__(256) void k_gemm12(const float* __restrict__ s1A,
                                                const float* __restrict__ s1B,
                                                const float* __restrict__ W1,
                                                const float* __restrict__ b1,
                                                const float* __restrict__ W2,
                                                const float* __restrict__ dis,
                                                float* __restrict__ hwA,
                                                float* __restrict__ hwB) {
    __shared__ float sW1[IN_CH * HID_CH];
    __shared__ float sW2[HID_CH * LAT_CH];
    __shared__ float sr[8][HID_CH + 1];
    int tid = threadIdx.x;
    for (int i = tid; i < IN_CH * HID_CH; i += 256) sW1[i] = W1[i];
    for (int i = tid; i < HID_CH * LAT_CH; i += 256) sW2[i] = W2[i];
    __syncthreads();
    int nl = tid >> 5, c1 = tid & 31;
    int node = blockIdx.x * 8 + nl;
    float r = 0.f;
    if (node < N_NODES) {
        float acc = b1[c1];
#pragma unroll
        for (int k = 0; k < 8; ++k)
            acc += s1A[(size_t)node * 8 + k] * sW1[k * HID_CH + c1];
#pragma unroll
        for (int k = 8; k < IN_CH; ++k)
            acc += s1B[(size_t)node * 8 + (k - 8)] * sW1[k * HID_CH + c1];
        r = fmaxf(acc, 0.f);   // ReLU
    }
    sr[nl][c1] = r;
    __syncthreads();
    if (tid < 128) {
        int nl2 = tid >> 4, c2 = tid & 15;
        int n2 = blockIdx.x * 8 + nl2;
        if (n2 < N_NODES) {
            float acc = 0.f;
#pragma unroll
            for (int k = 0; k < HID_CH; ++k)
                acc += sr[nl2][k] * sW2[k * LAT_CH + c2];
            acc *= dis[n2];    // premultiply for layer-2 messages
            if (c2 < 8) hwA[(size_t)n2 * 8 + c2] = acc;
            else        hwB[(size_t)n2 * 8 + (c2 - 8)] = acc;
        }
    }
}

extern "C" void kernel_launch(void* const* d_in, const int* in_sizes, int n_in,
                              void* d_out, int out_size, void* d_ws, size_t ws_size,
                              hipStream_t stream) {
    const float* x  = (const float*)d_in[0];
    const int*   ei = (const int*)d_in[1];
    const float* W1 = (const float*)d_in[2];
    const float* b1 = (const float*)d_in[3];
    const float* W2 = (const float*)d_in[4];
    const float* b2 = (const float*)d_in[5];
    float* out = (float*)d_out;

    const int* src = ei;
    const int* dst = ei + N_EDGES;

    // ws layout (bytes):
    //   bcur[196]  @ 0        | bbase[196] @ 1024 | off[N+1] @ 2048 (->402064)
    //   dis[N]     @ 402176   (->802176)
    //   srcs[E]    @ 802176   (12.8MB, ->13602176)
    //   buckets    @ 13602176 (196*18432*4 = 14.45MB) -- dead after sortB
    //   xnA/xnB/s1A/s1B alias buckets (4 x 3.2MB = 12.8MB <= 14.45MB)
    // peak ~28.1 MB
    char* ws = (char*)d_ws;
    int*   bcur    = (int*)(ws);
    int*   bbase   = (int*)(ws + 1024);
    int*   off     = (int*)(ws + 2048);
    float* dis     = (float*)(ws + 402176);
    int*   srcs    = (int*)(ws + 802176);
    int*   buckets = (int*)(ws + 13602176);
    float* xnA     = (float*)(ws + 13602176);
    float* xnB     = (float*)(ws + 13602176 + 3200000);
    float* s1A     = (float*)(ws + 13602176 + 2 * 3200000);
    float* s1B     = (float*)(ws + 13602176 + 3 * 3200000);
    float* hwA = xnA;  // xn dead after layer-1 agg passes
    float* hwB = xnB;

    const int NB_A   = (N_EDGES + TILE - 1) / TILE;        // 196
    const int NB_N16 = (N_NODES * 16 + 255) / 256;         // 6250
    const int NB_W   = ((N_NODES + 31) / 32 + 3) / 4;      // 32 nodes/wave, 4 waves/block
    const int NB_G   = (N_NODES + 7) / 8;                  // 12500

    k_zero   <<<1,     256, 0, stream>>>(bcur);
    k_binA   <<<NB_A, 1024, 0, stream>>>(src, dst, bcur, buckets);
    k_scanTop<<<1,     256, 0, stream>>>(bcur, bbase, off);
    k_sortB  <<<NBKT, 1024, 0, stream>>>(bcur, bbase, buckets, off, dis, srcs);
    k_xn     <<<NB_N16,256, 0, stream>>>(x, dis, xnA, xnB);
    k_agg    <<<NB_W,  256, 0, stream>>>(off, srcs, xnA, dis, nullptr, s1A, 8);
    k_agg    <<<NB_W,  256, 0, stream>>>(off, srcs, xnB, dis, nullptr, s1B, 8);
    k_gemm12 <<<NB_G,  256, 0, stream>>>(s1A, s1B, W1, b1, W2, dis, hwA, hwB);
    k_agg    <<<NB_W,  256, 0, stream>>>(off, srcs, hwA, dis, b2,     out,     16);
    k_agg    <<<NB_W,  256, 0, stream>>>(off, srcs, hwB, dis, b2 + 8, out + 8, 16);
}

// Round 9
// 304.430 us; speedup vs baseline: 1.4578x; 1.4578x over previous
//
#include <hip/hip_runtime.h>

// GCN 2-layer, N=100000, E=3200000, 13 -> 32 -> 16.
// Pipeline: coarse bucket sort by dst>>9 (512-node buckets) -> per-bucket LDS
// counting sort ONCE to compact global srcs/off/dis -> 4 aggregation passes:
// wave per 16 nodes, 32 edge-slots x 2 channel-quads (float4/lane), 20-shfl
// reduction per node, gathering from 3.2MB L2-resident half-channel tables.
// Messages premultiplied by dis[src]; dis[dst] + bias applied at finalize.
// NOTE: no nontemporal hints on srcs (round-8 lesson: NT killed line reuse).

constexpr int N_NODES = 100000;
constexpr int N_EDGES = 3200000;
constexpr int IN_CH  = 13;
constexpr int HID_CH = 32;
constexpr int LAT_CH = 16;

constexpr int BSZ  = 512;                       // nodes per bucket
constexpr int NBKT = (N_NODES + BSZ - 1) / BSZ; // 196
constexpr int BCAP = 18432;                     // mean 16384, sd 128 -> 16 sigma
constexpr int TILE = 16384;                     // edges per binA block (1024 thr x 16)

__global__ __launch_bounds__(256) void k_zero(int* __restrict__ bcur) {
    int i = threadIdx.x;
    if (i < NBKT) bcur[i] = 0;
}

// bucket by dst>>9; packed word = (dst&511)<<17 | src (26 bits).
// Edges staged in registers between hist and scatter (one global read).
__global__ __launch_bounds__(1024) void k_binA(const int* __restrict__ src,
                                               const int* __restrict__ dst,
                                               int* __restrict__ bcur,
                                               int* __restrict__ buckets) {
    __shared__ int h[NBKT], st[NBKT], cur[NBKT];
    int tid = threadIdx.x;
    if (tid < NBKT) h[tid] = 0;
    __syncthreads();
    int e0 = blockIdx.x * TILE;
    int rs[16], rd[16];
#pragma unroll
    for (int i = 0; i < 16; ++i) {
        int e = e0 + tid + i * 1024;
        if (e < N_EDGES) {
            rs[i] = src[e]; rd[i] = dst[e];
            atomicAdd(&h[rd[i] >> 9], 1);
        } else rd[i] = -1;
    }
    __syncthreads();
    if (tid < NBKT) {
        int c = h[tid];
        st[tid] = c ? atomicAdd(&bcur[tid], c) : 0;
        cur[tid] = 0;
    }
    __syncthreads();
#pragma unroll
    for (int i = 0; i < 16; ++i) {
        if (rd[i] >= 0) {
            int b = rd[i] >> 9;
            int p = st[b] + atomicAdd(&cur[b], 1);
            if (p < BCAP) buckets[(size_t)b * BCAP + p] = rs[i] | ((rd[i] & 511) << 17);
        }
    }
}

// exclusive scan of clamped bucket counts; also writes off[N] sentinel
__global__ __launch_bounds__(256) void k_scanTop(const int* __restrict__ bcur,
                                                 int* __restrict__ bbase,
                                                 int* __restrict__ off) {
    __shared__ int v[256];
    int tid = threadIdx.x;
    int c = (tid < NBKT) ? min(bcur[tid], BCAP) : 0;
    v[tid] = c;
    __syncthreads();
    for (int d = 1; d < 256; d <<= 1) {
        int a = v[tid];
        int u = (tid >= d) ? v[tid - d] : 0;
        __syncthreads();
        v[tid] = a + u;
        __syncthreads();
    }
    if (tid < NBKT) bbase[tid] = v[tid] - c;
    if (tid == 255) off[N_NODES] = v[255];
}

// per-bucket counting sort ONCE: reg-staged words (const-index unroll),
// LDS hist over 512 nodes -> scan -> compact global srcs; emits off, dis.
__global__ __launch_bounds__(1024) void k_sortB(const int* __restrict__ bcur,
                                                const int* __restrict__ bbase,
                                                const int* __restrict__ buckets,
                                                int* __restrict__ off,
                                                float* __restrict__ dis,
                                                int* __restrict__ srcs) {
    __shared__ int h[BSZ], ex[BSZ], cur[BSZ];
    int b = blockIdx.x, tid = threadIdx.x;
    int cnt = min(bcur[b], BCAP);
    int base = bbase[b];
    const int* bw = buckets + (size_t)b * BCAP;
    if (tid < BSZ) h[tid] = 0;
    __syncthreads();
    int rw[18];                               // BCAP/1024 = 18
#pragma unroll
    for (int i = 0; i < 18; ++i) {
        int idx = tid + i * 1024;
        rw[i] = (idx < cnt) ? __builtin_nontemporal_load(bw + idx) : -1;
        if (rw[i] >= 0) atomicAdd(&h[rw[i] >> 17], 1);
    }
    __syncthreads();
    if (tid < BSZ) ex[tid] = h[tid];
    __syncthreads();
    for (int d = 1; d < BSZ; d <<= 1) {       // inclusive scan over 512
        int a = 0, u = 0;
        if (tid < BSZ) { a = ex[tid]; if (tid >= d) u = ex[tid - d]; }
        __syncthreads();
        if (tid < BSZ) ex[tid] = a + u;
        __syncthreads();
    }
    if (tid < BSZ) {
        int excl = ex[tid] - h[tid];
        int node = b * BSZ + tid;
        if (node < N_NODES) {
            off[node] = base + excl;
            dis[node] = rsqrtf((float)(h[tid] + 1));   // +1 self-loop
        }
        cur[tid] = excl;
    }
    __syncthreads();
#pragma unroll
    for (int i = 0; i < 18; ++i) {
        if (rw[i] >= 0) {
            int p = atomicAdd(&cur[rw[i] >> 17], 1);
            srcs[base + p] = rw[i] & 131071;
        }
    }
}

// split 16-ch (13 real + 3 zero) premultiplied features into two 8-ch tables
__global__ __launch_bounds__(256) void k_xn(const float* __restrict__ x,
                                            const float* __restrict__ dis,
                                            float* __restrict__ xnA,
                                            float* __restrict__ xnB) {
    int idx = blockIdx.x * 256 + threadIdx.x;
    if (idx >= N_NODES * 16) return;
    int node = idx >> 4, c = idx & 15;
    float v = (c < IN_CH) ? x[node * IN_CH + c] * dis[node] : 0.f;
    if (c < 8) xnA[node * 8 + c] = v;
    else       xnB[node * 8 + (c - 8)] = v;
}

// wave per 16 nodes; per node: 32 edge-slots x 2 channel-quads (float4/lane),
// coalesced srcs (32 consecutive words, lane-pairs broadcast), 5-level shfl
// reduce (20 shfl/node), 2-lane float4 finalize write.
__global__ __launch_bounds__(256) void k_agg(const int* __restrict__ off,
                                             const int* __restrict__ srcs,
                                             const float* __restrict__ tab,   // N x 8
                                             const float* __restrict__ dis,
                                             const float* __restrict__ bias,  // 8 floats or null
                                             float* __restrict__ outp,
                                             int ostride) {
    int wv   = (blockIdx.x * 256 + threadIdx.x) >> 6;   // global wave id
    int lane = threadIdx.x & 63;
    int slot = lane >> 1;       // edge slot 0..31
    int q    = lane & 1;        // channel quad (floats q*4 .. q*4+3)
    int n0 = wv * 16;
    if (n0 >= N_NODES) return;
    int nend = min(n0 + 16, N_NODES);
    for (int node = n0; node < nend; ++node) {
        int beg = off[node], end = off[node + 1];
        float a0 = 0.f, a1 = 0.f, a2 = 0.f, a3 = 0.f;
        for (int k = beg + slot; k < end; k += 32) {
            int s = srcs[k];
            const float4 v = *(const float4*)(tab + (size_t)s * 8 + q * 4);
            a0 += v.x; a1 += v.y; a2 += v.z; a3 += v.w;
        }
#pragma unroll
        for (int m = 2; m <= 32; m <<= 1) {   // reduce over slot bits 1..5
            a0 += __shfl_xor(a0, m);
            a1 += __shfl_xor(a1, m);
            a2 += __shfl_xor(a2, m);
            a3 += __shfl_xor(a3, m);
        }
        if (slot == 0) {
            const float4 self = *(const float4*)(tab + (size_t)node * 8 + q * 4);
            float dn = dis[node];
            float4 r;
            r.x = dn * (a0 + self.x);
            r.y = dn * (a1 + self.y);
            r.z = dn * (a2 + self.z);
            r.w = dn * (a3 + self.w);
            if (bias) {
                const float4 bq = *(const float4*)(bias + q * 4);
                r.x += bq.x; r.y += bq.y; r.z += bq.z; r.w += bq.w;
            }
            *(float4*)(outp + (size_t)node * ostride + q * 4) = r;
        }
    }
}

// fused: hw{A,B} = (relu(s1 @ W1 + b1) @ W2) * dis   (split in/out tables)
__global__ __launch_bounds__(256) void k_gemm12(const float* __restrict__ s1A,
                                                const float* __restrict__ s1B,
                                                const float* __restrict__ W1,
                                                const float* __restrict__ b1,
                                                const float* __restrict__ W2,
                                                const float* __restrict__ dis,
                                                float* __restrict__ hwA,
                                                float* __restrict__ hwB) {
    __shared__ float sW1[IN_CH * HID_CH];
    __shared__ float sW2[HID_CH * LAT_CH];
    __shared__ float sr[8][HID_CH + 1];
    int tid = threadIdx.x;
    for (int i = tid; i < IN_CH * HID_CH; i += 256) sW1[i] = W1[i];
    for (int i = tid; i < HID_CH * LAT_CH; i += 256) sW2[i] = W2[i];
    __syncthreads();
    int nl = tid >> 5, c1 = tid & 31;
    int node = blockIdx.x * 8 + nl;
    float r = 0.f;
    if (node < N_NODES) {
        float acc = b1[c1];
#pragma unroll
        for (int k = 0; k < 8; ++k)
            acc += s1A[(size_t)node * 8 + k] * sW1[k * HID_CH + c1];
#pragma unroll
        for (int k = 8; k < IN_CH; ++k)
            acc += s1B[(size_t)node * 8 + (k - 8)] * sW1[k * HID_CH + c1];
        r = fmaxf(acc, 0.f);   // ReLU
    }
    sr[nl][c1] = r;
    __syncthreads();
    if (tid < 128) {
        int nl2 = tid >> 4, c2 = tid & 15;
        int n2 = blockIdx.x * 8 + nl2;
        if (n2 < N_NODES) {
            float acc = 0.f;
#pragma unroll
            for (int k = 0; k < HID_CH; ++k)
                acc += sr[nl2][k] * sW2[k * LAT_CH + c2];
            acc *= dis[n2];    // premultiply for layer-2 messages
            if (c2 < 8) hwA[(size_t)n2 * 8 + c2] = acc;
            else        hwB[(size_t)n2 * 8 + (c2 - 8)] = acc;
        }
    }
}

extern "C" void kernel_launch(void* const* d_in, const int* in_sizes, int n_in,
                              void* d_out, int out_size, void* d_ws, size_t ws_size,
                              hipStream_t stream) {
    const float* x  = (const float*)d_in[0];
    const int*   ei = (const int*)d_in[1];
    const float* W1 = (const float*)d_in[2];
    const float* b1 = (const float*)d_in[3];
    const float* W2 = (const float*)d_in[4];
    const float* b2 = (const float*)d_in[5];
    float* out = (float*)d_out;

    const int* src = ei;
    const int* dst = ei + N_EDGES;

    // ws layout (bytes):
    //   bcur[196]  @ 0        | bbase[196] @ 1024 | off[N+1] @ 2048 (->402064)
    //   dis[N]     @ 402176   (->802176)
    //   srcs[E]    @ 802176   (12.8MB, ->13602176)
    //   buckets    @ 13602176 (196*18432*4 = 14.45MB) -- dead after sortB
    //   xnA/xnB/s1A/s1B alias buckets (4 x 3.2MB = 12.8MB <= 14.45MB)
    // peak ~28.1 MB
    char* ws = (char*)d_ws;
    int*   bcur    = (int*)(ws);
    int*   bbase   = (int*)(ws + 1024);
    int*   off     = (int*)(ws + 2048);
    float* dis     = (float*)(ws + 402176);
    int*   srcs    = (int*)(ws + 802176);
    int*   buckets = (int*)(ws + 13602176);
    float* xnA     = (float*)(ws + 13602176);
    float* xnB     = (float*)(ws + 13602176 + 3200000);
    float* s1A     = (float*)(ws + 13602176 + 2 * 3200000);
    float* s1B     = (float*)(ws + 13602176 + 3 * 3200000);
    float* hwA = xnA;  // xn dead after layer-1 agg passes
    float* hwB = xnB;

    const int NB_A   = (N_EDGES + TILE - 1) / TILE;        // 196
    const int NB_N16 = (N_NODES * 16 + 255) / 256;         // 6250
    const int NB_W   = ((N_NODES + 15) / 16 + 3) / 4;      // 16 nodes/wave, 4 waves/block
    const int NB_G   = (N_NODES + 7) / 8;                  // 12500

    k_zero   <<<1,     256, 0, stream>>>(bcur);
    k_binA   <<<NB_A, 1024, 0, stream>>>(src, dst, bcur, buckets);
    k_scanTop<<<1,     256, 0, stream>>>(bcur, bbase, off);
    k_sortB  <<<NBKT, 1024, 0, stream>>>(bcur, bbase, buckets, off, dis, srcs);
    k_xn     <<<NB_N16,256, 0, stream>>>(x, dis, xnA, xnB);
    k_agg    <<<NB_W,  256, 0, stream>>>(off, srcs, xnA, dis, nullptr, s1A, 8);
    k_agg    <<<NB_W,  256, 0, stream>>>(off, srcs, xnB, dis, nullptr, s1B, 8);
    k_gemm12 <<<NB_G,  256, 0, stream>>>(s1A, s1B, W1, b1, W2, dis, hwA, hwB);
    k_agg    <<<NB_W,  256, 0, stream>>>(off, srcs, hwA, dis, b2,     out,     16);
    k_agg    <<<NB_W,  256, 0, stream>>>(off, srcs, hwB, dis, b2 + 8, out + 8, 16);
}